// Round 1
// baseline (327.124 us; speedup 1.0000x reference)
//
#include <hip/hip_runtime.h>
#include <stdint.h>

// Binarized 5-layer MLP, B=32768, dims 784->256->256->256->256->10.
// All matmuls done as XOR+popcount on packed sign bits: h = in - 2*d,
// d = popcount(a_bits ^ w_bits). BN stats derived exactly from integer
// sums of d per column (Sum d -> int32 atomics, Sum d^2 -> uint64 atomics).
// binarize(BN(h)) == (A*d + C >= 0) with per-column A = -2*g*s, C = 2*g*s*mean_d + b.

#define BATCH 32768
#define ROWS_PER_BLK 64
#define NBLK (BATCH / ROWS_PER_BLK)   // 512

typedef unsigned long long u64;

// ---------------- workspace layout (bytes) ----------------
#define OFF_A0    0u                         // 32768*16*8 = 4 MiB (13 words used, stride 16)
#define OFF_H0    4194304u                   // 32768*256*2 = 16 MiB (int16 h of layer 0)
#define OFF_A1    20971520u                  // 32768*4*8 = 1 MiB each
#define OFF_A2    22020096u
#define OFF_A3    23068672u
#define OFF_A4    24117248u
#define OFF_WB0   25165824u                  // 256*16*8 = 32 KiB
#define OFF_WB1   25198592u                  // 256*4*8 = 8 KiB
#define OFF_WB2   25206784u
#define OFF_WB3   25214976u
#define OFF_WB4   25223168u                  // 10*4*8 = 320 B (pad 512)
#define OFF_SUMD  25223680u                  // int32 [5][256] = 5120 B
#define OFF_SUMDD 25228800u                  // uint64 [5][256] = 10240 B
#define STATS_BYTES (5120u + 10240u)
// total ws needed ~= 25.3 MB

// ---------------- pack helpers ----------------
// 784-elem row -> 13 u64 words (permuted-but-consistent bit order; pads zero).
__device__ __forceinline__ void pack784(const float* __restrict__ src,
                                        u64* __restrict__ dst, float thr, int lane) {
  u64 w[13];
  const float4* s4 = (const float4*)src;
#pragma unroll
  for (int j = 0; j < 3; ++j) {
    float4 v = s4[j * 64 + lane];
    w[4 * j + 0] = __ballot(v.x >= thr);
    w[4 * j + 1] = __ballot(v.y >= thr);
    w[4 * j + 2] = __ballot(v.z >= thr);
    w[4 * j + 3] = __ballot(v.w >= thr);
  }
  float4 v = make_float4(-1.f, -1.f, -1.f, -1.f);
  if (lane < 4) v = s4[192 + lane];
  u64 m0 = __ballot(v.x >= thr) & 0xFull;
  u64 m1 = __ballot(v.y >= thr) & 0xFull;
  u64 m2 = __ballot(v.z >= thr) & 0xFull;
  u64 m3 = __ballot(v.w >= thr) & 0xFull;
  w[12] = m0 | (m1 << 4) | (m2 << 8) | (m3 << 12);
  u64 sel = 0;
#pragma unroll
  for (int i = 0; i < 13; ++i) sel = (lane == i) ? w[i] : sel;
  if (lane < 16) dst[lane] = sel;   // words 13..15 zero-padded
}

// 256-elem row -> 4 u64 words; bit l of word j <-> element 64*j+l
// (matches the in-kernel ballot order used by the B kernels).
__device__ __forceinline__ void pack256(const float* __restrict__ src,
                                        u64* __restrict__ dst, int lane) {
  u64 w[4];
#pragma unroll
  for (int j = 0; j < 4; ++j) {
    float v = src[j * 64 + lane];
    w[j] = __ballot(v >= 0.0f);
  }
  u64 sel = 0;
#pragma unroll
  for (int i = 0; i < 4; ++i) sel = (lane == i) ? w[i] : sel;
  if (lane < 4) dst[lane] = sel;
}

// ---------------- kernel: pack x and all weights ----------------
__global__ __launch_bounds__(256) void pack_all(
    const float* __restrict__ x,
    const float* __restrict__ W0, const float* __restrict__ W1,
    const float* __restrict__ W2, const float* __restrict__ W3,
    const float* __restrict__ W4,
    u64* __restrict__ a0, u64* __restrict__ wb0, u64* __restrict__ wb1,
    u64* __restrict__ wb2, u64* __restrict__ wb3, u64* __restrict__ wb4) {
  const int wave = threadIdx.x >> 6, lane = threadIdx.x & 63;
  const int blk = blockIdx.x;
  if (blk < 8192) {                       // x rows: binarize(x - 0.5) == (x >= 0.5)
    int row = blk * 4 + wave;
    pack784(x + (size_t)row * 784, a0 + (size_t)row * 16, 0.5f, lane);
  } else if (blk < 8256) {                // W0: 256 rows of 784
    int row = (blk - 8192) * 4 + wave;
    pack784(W0 + (size_t)row * 784, wb0 + (size_t)row * 16, 0.0f, lane);
  } else if (blk < 8320) {                // W1
    int row = (blk - 8256) * 4 + wave;
    pack256(W1 + (size_t)row * 256, wb1 + (size_t)row * 4, lane);
  } else if (blk < 8384) {                // W2
    int row = (blk - 8320) * 4 + wave;
    pack256(W2 + (size_t)row * 256, wb2 + (size_t)row * 4, lane);
  } else if (blk < 8448) {                // W3
    int row = (blk - 8384) * 4 + wave;
    pack256(W3 + (size_t)row * 256, wb3 + (size_t)row * 4, lane);
  } else {                                // W4: 10 rows
    int row = (blk - 8448) * 4 + wave;
    if (row < 10) pack256(W4 + (size_t)row * 256, wb4 + (size_t)row * 4, lane);
  }
}

// ---------------- layer 0 matmul + stats (materialize h0 as int16) ----------------
__global__ __launch_bounds__(256) void mm0_kernel(
    const u64* __restrict__ a0, const u64* __restrict__ wb0,
    short* __restrict__ h0, int* __restrict__ sumd, u64* __restrict__ sumdd) {
  const int col = threadIdx.x;
  const int row0 = blockIdx.x * ROWS_PER_BLK;
  u64 w[13];
#pragma unroll
  for (int i = 0; i < 13; ++i) w[i] = wb0[col * 16 + i];
  int sd = 0, sdd = 0;   // per-thread: d<=784 -> sdd <= 64*784^2 = 39.3M, fits int32
  for (int r = 0; r < ROWS_PER_BLK; ++r) {
    const u64* ap = a0 + (size_t)(row0 + r) * 16;
    int d = 0;
#pragma unroll
    for (int i = 0; i < 13; ++i) d += __popcll(ap[i] ^ w[i]);
    h0[(size_t)(row0 + r) * 256 + col] = (short)(784 - 2 * d);
    sd += d; sdd += d * d;
  }
  atomicAdd(&sumd[col], sd);
  atomicAdd(&sumdd[col], (u64)(unsigned)sdd);
}

// ---------------- B0: binarize h0 -> a1 bits, + layer-1 stats ----------------
__global__ __launch_bounds__(256) void b0_kernel(
    const short* __restrict__ h0,
    const int* __restrict__ sumd0, const u64* __restrict__ sumdd0,
    const float* __restrict__ gamma0, const float* __restrict__ beta0,
    u64* __restrict__ a1, const u64* __restrict__ wb1,
    int* __restrict__ sumd1, u64* __restrict__ sumdd1) {
  const int tid = threadIdx.x, lane = tid & 63, j = tid >> 6;
  const int row0 = blockIdx.x * ROWS_PER_BLK;
  // per-column BN params from exact integer sums
  double md  = (double)sumd0[tid]  * (1.0 / 32768.0);
  double mdd = (double)sumdd0[tid] * (1.0 / 32768.0);
  float var = (float)(4.0 * (mdd - md * md));
  float s   = rsqrtf(var + 1e-5f);
  float gs  = gamma0[tid] * s;
  float mh  = (float)(784.0 - 2.0 * md);
  float bb  = beta0[tid];
  __shared__ u64 ab[ROWS_PER_BLK * 4];
  for (int r = 0; r < ROWS_PER_BLK; ++r) {
    float hv = (float)h0[(size_t)(row0 + r) * 256 + tid];
    bool bit = fmaf(gs, hv - mh, bb) >= 0.0f;
    u64 m = __ballot(bit);
    if (lane == 0) ab[r * 4 + j] = m;
  }
  __syncthreads();
  a1[(size_t)row0 * 4 + tid] = ab[tid];          // 64 rows * 4 words = 256 u64, coalesced
  // phase 2: layer-1 stats
  u64 w[4];
#pragma unroll
  for (int i = 0; i < 4; ++i) w[i] = wb1[tid * 4 + i];
  int sd = 0, sdd = 0;
  for (int r = 0; r < ROWS_PER_BLK; ++r) {
    int d = __popcll(ab[r * 4 + 0] ^ w[0]) + __popcll(ab[r * 4 + 1] ^ w[1]) +
            __popcll(ab[r * 4 + 2] ^ w[2]) + __popcll(ab[r * 4 + 3] ^ w[3]);
    sd += d; sdd += d * d;
  }
  atomicAdd(&sumd1[tid], sd);
  atomicAdd(&sumdd1[tid], (u64)(unsigned)sdd);
}

// ---------------- mid layers: recompute d_k, binarize -> a_{k+1}, stats_{k+1} ----------------
__global__ __launch_bounds__(256) void bmid_kernel(
    const u64* __restrict__ aPrev, const u64* __restrict__ wbPrev,
    const int* __restrict__ sumdP, const u64* __restrict__ sumddP,
    const float* __restrict__ gammaP, const float* __restrict__ betaP,
    u64* __restrict__ aNext, const u64* __restrict__ wbNext,
    int* __restrict__ sumdN, u64* __restrict__ sumddN, int nColsNext) {
  const int tid = threadIdx.x, lane = tid & 63, j = tid >> 6;
  const int row0 = blockIdx.x * ROWS_PER_BLK;
  double md  = (double)sumdP[tid]  * (1.0 / 32768.0);
  double mdd = (double)sumddP[tid] * (1.0 / 32768.0);
  float var = (float)(4.0 * (mdd - md * md));
  float s   = rsqrtf(var + 1e-5f);
  float gs  = gammaP[tid] * s;
  float A   = -2.0f * gs;
  float C   = fmaf(gs, (float)(2.0 * md), betaP[tid]);
  u64 w[4];
#pragma unroll
  for (int i = 0; i < 4; ++i) w[i] = wbPrev[tid * 4 + i];
  __shared__ u64 ab[ROWS_PER_BLK * 4];
  for (int r = 0; r < ROWS_PER_BLK; ++r) {
    const u64* ap = aPrev + (size_t)(row0 + r) * 4;
    int d = __popcll(ap[0] ^ w[0]) + __popcll(ap[1] ^ w[1]) +
            __popcll(ap[2] ^ w[2]) + __popcll(ap[3] ^ w[3]);
    bool bit = fmaf(A, (float)d, C) >= 0.0f;
    u64 m = __ballot(bit);
    if (lane == 0) ab[r * 4 + j] = m;
  }
  __syncthreads();
  aNext[(size_t)row0 * 4 + tid] = ab[tid];
  if (tid < nColsNext) {
    u64 wn[4];
#pragma unroll
    for (int i = 0; i < 4; ++i) wn[i] = wbNext[tid * 4 + i];
    int sd = 0, sdd = 0;
    for (int r = 0; r < ROWS_PER_BLK; ++r) {
      int d = __popcll(ab[r * 4 + 0] ^ wn[0]) + __popcll(ab[r * 4 + 1] ^ wn[1]) +
              __popcll(ab[r * 4 + 2] ^ wn[2]) + __popcll(ab[r * 4 + 3] ^ wn[3]);
      sd += d; sdd += d * d;
    }
    atomicAdd(&sumdN[tid], sd);
    atomicAdd(&sumddN[tid], (u64)(unsigned)sdd);
  }
}

// ---------------- final: layer-4 matmul + BN + softmax ----------------
__global__ __launch_bounds__(256) void b4_kernel(
    const u64* __restrict__ a4, const u64* __restrict__ wb4,
    const int* __restrict__ sumd4, const u64* __restrict__ sumdd4,
    const float* __restrict__ gamma4, const float* __restrict__ beta4,
    float* __restrict__ out) {
  __shared__ float sA[10], sC[10];
  __shared__ u64 w4s[40];
  const int tid = threadIdx.x;
  if (tid < 40) w4s[tid] = wb4[tid];
  if (tid < 10) {
    double md  = (double)sumd4[tid]  * (1.0 / 32768.0);
    double mdd = (double)sumdd4[tid] * (1.0 / 32768.0);
    float var = (float)(4.0 * (mdd - md * md));
    float s   = rsqrtf(var + 1e-5f);
    float gs  = gamma4[tid] * s;
    sA[tid] = -2.0f * gs;
    sC[tid] = fmaf(gs, (float)(2.0 * md), beta4[tid]);
  }
  __syncthreads();
  const int row = blockIdx.x * 256 + tid;
  u64 a[4];
#pragma unroll
  for (int i = 0; i < 4; ++i) a[i] = a4[(size_t)row * 4 + i];
  float y[10];
  float mx = -1e30f;
#pragma unroll
  for (int c = 0; c < 10; ++c) {
    int d = __popcll(a[0] ^ w4s[c * 4 + 0]) + __popcll(a[1] ^ w4s[c * 4 + 1]) +
            __popcll(a[2] ^ w4s[c * 4 + 2]) + __popcll(a[3] ^ w4s[c * 4 + 3]);
    y[c] = fmaf(sA[c], (float)d, sC[c]);
    mx = fmaxf(mx, y[c]);
  }
  float sum = 0.0f;
#pragma unroll
  for (int c = 0; c < 10; ++c) { y[c] = __expf(y[c] - mx); sum += y[c]; }
  float inv = 1.0f / sum;
#pragma unroll
  for (int c = 0; c < 10; ++c) out[(size_t)row * 10 + c] = y[c] * inv;
}

// ---------------- host ----------------
extern "C" void kernel_launch(void* const* d_in, const int* in_sizes, int n_in,
                              void* d_out, int out_size, void* d_ws, size_t ws_size,
                              hipStream_t stream) {
  (void)in_sizes; (void)n_in; (void)out_size; (void)ws_size;
  const float* x  = (const float*)d_in[0];
  const float* W0 = (const float*)d_in[1];
  const float* g0 = (const float*)d_in[2];
  const float* bb0 = (const float*)d_in[3];
  const float* W1 = (const float*)d_in[4];
  const float* g1 = (const float*)d_in[5];
  const float* bb1 = (const float*)d_in[6];
  const float* W2 = (const float*)d_in[7];
  const float* g2 = (const float*)d_in[8];
  const float* bb2 = (const float*)d_in[9];
  const float* W3 = (const float*)d_in[10];
  const float* g3 = (const float*)d_in[11];
  const float* bb3 = (const float*)d_in[12];
  const float* W4 = (const float*)d_in[13];
  const float* g4 = (const float*)d_in[14];
  const float* bb4 = (const float*)d_in[15];

  char* ws = (char*)d_ws;
  u64*   a0  = (u64*)(ws + OFF_A0);
  short* h0  = (short*)(ws + OFF_H0);
  u64*   a1  = (u64*)(ws + OFF_A1);
  u64*   a2  = (u64*)(ws + OFF_A2);
  u64*   a3  = (u64*)(ws + OFF_A3);
  u64*   a4  = (u64*)(ws + OFF_A4);
  u64*   wb0 = (u64*)(ws + OFF_WB0);
  u64*   wb1 = (u64*)(ws + OFF_WB1);
  u64*   wb2 = (u64*)(ws + OFF_WB2);
  u64*   wb3 = (u64*)(ws + OFF_WB3);
  u64*   wb4 = (u64*)(ws + OFF_WB4);
  int*   sumd  = (int*)(ws + OFF_SUMD);
  u64*   sumdd = (u64*)(ws + OFF_SUMDD);

  hipMemsetAsync(ws + OFF_SUMD, 0, STATS_BYTES, stream);

  pack_all<<<8451, 256, 0, stream>>>(x, W0, W1, W2, W3, W4, a0, wb0, wb1, wb2, wb3, wb4);
  mm0_kernel<<<NBLK, 256, 0, stream>>>(a0, wb0, h0, sumd, sumdd);
  b0_kernel<<<NBLK, 256, 0, stream>>>(h0, sumd, sumdd, g0, bb0, a1, wb1, sumd + 256, sumdd + 256);
  bmid_kernel<<<NBLK, 256, 0, stream>>>(a1, wb1, sumd + 256, sumdd + 256, g1, bb1,
                                        a2, wb2, sumd + 512, sumdd + 512, 256);
  bmid_kernel<<<NBLK, 256, 0, stream>>>(a2, wb2, sumd + 512, sumdd + 512, g2, bb2,
                                        a3, wb3, sumd + 768, sumdd + 768, 256);
  bmid_kernel<<<NBLK, 256, 0, stream>>>(a3, wb3, sumd + 768, sumdd + 768, g3, bb3,
                                        a4, wb4, sumd + 1024, sumdd + 1024, 10);
  b4_kernel<<<BATCH / 256, 256, 0, stream>>>(a4, wb4, sumd + 1024, sumdd + 1024, g4, bb4,
                                             (float*)d_out);
}